// Round 11
// baseline (290.655 us; speedup 1.0000x reference)
//
#include <hip/hip_runtime.h>

#define DMODEL 1024
#define NHEADS 16
#define HDIM   64
#define BB     4
#define TT     2048

typedef __attribute__((ext_vector_type(8))) short bf16x8;
typedef __attribute__((ext_vector_type(4))) short bf16x4;
typedef __attribute__((ext_vector_type(4))) float f32x4;

#if __has_builtin(__builtin_amdgcn_exp2f)
#define EXP2(x) __builtin_amdgcn_exp2f(x)
#else
#define EXP2(x) __expf(0.69314718f * (x))
#endif

// 0.125 * log2(e): folded into Q at projection time
#define C1SCALE 0.18033688f

__device__ inline void async16(const void* g, void* l) {
  __builtin_amdgcn_global_load_lds(
      (const __attribute__((address_space(1))) unsigned int*)g,
      (__attribute__((address_space(3))) unsigned int*)l,
      16, 0, 0);
}

__device__ inline unsigned short f2bf(float x) {
  union { float f; unsigned int u; } c; c.f = x;
  unsigned int r = (c.u + 0x7FFFu + ((c.u >> 16) & 1u)) >> 16;
  return (unsigned short)r;
}

// rne-pack two fp32 -> one u32 (lo,hi bf16) -- same rounding as f2bf
__device__ inline unsigned int pk2(float a, float b) {
  union { float f; unsigned int u; } ua, ub; ua.f = a; ub.f = b;
  unsigned int ra = (ua.u + 0x7FFFu + ((ua.u >> 16) & 1u)) >> 16;
  unsigned int rb = (ub.u + 0x7FFFu + ((ub.u >> 16) & 1u)) & 0xFFFF0000u;
  return ra | rb;
}

// pack two fp32 -> bf16x2, TRUNCATING (P >= 0; identical truncation feeds both
// numerator (PV) and denominator (P*ones) so the uniform bias cancels in O)
__device__ inline unsigned int pkbf(float x, float y) {
  union { float f; unsigned int u; } a, b; a.f = x; b.f = y;
  return __builtin_amdgcn_perm(b.u, a.u, 0x07060302u);
}

// Weights-only conversion: wq/wk/wv -> wqkvb, wo -> wob (1024 blk each).
// x is consumed as fp32 directly by gemm_qkv (inline conversion).
__global__ __launch_bounds__(256) void cvt_all(
    const float* __restrict__ wq, const float* __restrict__ wk,
    const float* __restrict__ wv, const float* __restrict__ wo,
    unsigned short* __restrict__ wqkvb, unsigned short* __restrict__ wob)
{
  int bid = blockIdx.x;
  int w = bid >> 10, r = bid & 1023;
  size_t off = (size_t)r * 1024;
  const float* src; unsigned short* dst;
  if (w == 0)      { src = wq; dst = wqkvb; }
  else if (w == 1) { src = wk; dst = wqkvb + 1048576; }
  else if (w == 2) { src = wv; dst = wqkvb + 2097152; }
  else             { src = wo; dst = wob; }
  size_t i = off + threadIdx.x * 4;
  float4 v = *(const float4*)(src + i);
  ushort4 o;
  o.x = f2bf(v.x); o.y = f2bf(v.y); o.z = f2bf(v.z); o.w = f2bf(v.w);
  *(ushort4*)(dst + i) = o;
}

// Fused QKV projection: A = x (fp32, 8192x1024, converted inline),
// W = wqkvb (bf16 3072x1024), y = A W^T.  R8 structure: 8 waves x (32x64
// per-wave tile, 32 AGPR acc), BK=64, XOR-8 swizzle, double-buffered.
// A-operand pipeline: load fp32->regs after barrier, MFMA compute, then
// cvt+ds_write -- the vmcnt wait lands after a full compute phase.
// Q output pre-scaled by C1SCALE.
__global__ __launch_bounds__(512, 4) void gemm_qkv(
    const float* __restrict__ X, const unsigned short* __restrict__ W,
    unsigned short* __restrict__ qw, unsigned short* __restrict__ kw,
    unsigned short* __restrict__ vtw)
{
  __shared__ unsigned short As[2][128 * 64];
  __shared__ unsigned short Bs[2][128 * 64];
  const int tid  = threadIdx.x;
  const int lane = tid & 63;
  const int wave = tid >> 6;           // 0..7
  const int lo   = lane & 15, q4 = lane >> 4;
  const int lo7  = lane & 7;
  const int wm   = wave & 3, wn = wave >> 2;  // 32-row quarter, 64-col half
  const int m0 = blockIdx.y * 128, n0 = blockIdx.x * 128;
  const int mid = blockIdx.x >> 3;

  f32x4 acc[2][4] = {};

  // A staging via registers (fp32 -> bf16 inline)
  const int arow = tid >> 2, at = tid & 3;
  const int ac0 = (((at * 2)     ^ (arow & 7)) * 8);
  const int ac1 = (((at * 2 + 1) ^ (arow & 7)) * 8);
  const float* xsrc = X + (size_t)(m0 + arow) * DMODEL + at * 16;
  float4 fr[4];

  auto loadA = [&](int k0) {
#pragma unroll
    for (int j = 0; j < 4; ++j) fr[j] = *(const float4*)(xsrc + k0 + j * 4);
  };
  auto writeA = [&](int buf) {
    uint4 q0, q1;
    q0.x = pk2(fr[0].x, fr[0].y); q0.y = pk2(fr[0].z, fr[0].w);
    q0.z = pk2(fr[1].x, fr[1].y); q0.w = pk2(fr[1].z, fr[1].w);
    q1.x = pk2(fr[2].x, fr[2].y); q1.y = pk2(fr[2].z, fr[2].w);
    q1.z = pk2(fr[3].x, fr[3].y); q1.w = pk2(fr[3].z, fr[3].w);
    *(uint4*)&As[buf][arow * 64 + ac0] = q0;
    *(uint4*)&As[buf][arow * 64 + ac1] = q1;
  };
  auto stageW = [&](int k0, int buf) {
#pragma unroll
    for (int i = 0; i < 2; ++i) {
      int ci = i * 512 + tid;          // 0..1023
      int row = ci >> 3;
      int c = (ci & 7) ^ (row & 7);
      async16(W + (size_t)(n0 + row) * DMODEL + k0 + c * 8, (char*)Bs[buf] + ci * 16);
    }
  };

  loadA(0); stageW(0, 0); writeA(0);
  for (int it = 0; it < DMODEL / 64; ++it) {
    const int buf = it & 1;
    __syncthreads();  // buf(it) resident (A lgkm-drained, W vmcnt-drained)
    if (it + 1 < DMODEL / 64) { loadA((it + 1) * 64); stageW((it + 1) * 64, buf ^ 1); }
#pragma unroll
    for (int hh = 0; hh < 2; ++hh) {
      bf16x8 af[2], bf[4];
#pragma unroll
      for (int mi = 0; mi < 2; ++mi)
        af[mi] = *(const bf16x8*)&As[buf][(wm * 32 + mi * 16 + lo) * 64 + ((hh * 4 + q4) ^ lo7) * 8];
#pragma unroll
      for (int ni = 0; ni < 4; ++ni)
        bf[ni] = *(const bf16x8*)&Bs[buf][(wn * 64 + ni * 16 + lo) * 64 + ((hh * 4 + q4) ^ lo7) * 8];
#pragma unroll
      for (int mi = 0; mi < 2; ++mi)
#pragma unroll
        for (int ni = 0; ni < 4; ++ni)
          acc[mi][ni] = __builtin_amdgcn_mfma_f32_16x16x32_bf16(af[mi], bf[ni], acc[mi][ni], 0, 0, 0);
    }
    if (it + 1 < DMODEL / 64) writeA(buf ^ 1);  // vmcnt wait hidden by compute
  }

  unsigned short* dst = (mid == 0) ? qw : (mid == 1) ? kw : vtw;
  const float sc = (mid == 0) ? C1SCALE : 1.0f;
#pragma unroll
  for (int mi = 0; mi < 2; ++mi) {
#pragma unroll
    for (int ni = 0; ni < 4; ++ni) {
#pragma unroll
      for (int r = 0; r < 4; ++r) {
        int m = m0 + wm * 32 + mi * 16 + q4 * 4 + r;
        int nl = ((blockIdx.x & 7) * 128) + wn * 64 + ni * 16 + lo;
        float v = acc[mi][ni][r] * sc;
        int b = m >> 11, t = m & (TT - 1);
        int h = nl >> 6, d = nl & 63;
        if (mid == 2)
          dst[(((size_t)(b * NHEADS + h)) * HDIM + d) * TT + t] = f2bf(v);
        else
          dst[(((size_t)(b * NHEADS + h)) * TT + t) * HDIM + d] = f2bf(v);
      }
    }
  }
}

// Output projection: C = A W^T + bias, fp32 out. R8 structure (all-bf16 inputs,
// pure global_load_lds staging, BK=64 dbuf).
__global__ __launch_bounds__(512, 4) void gemm_out(
    const unsigned short* __restrict__ A, const unsigned short* __restrict__ W,
    const float* __restrict__ bias, float* __restrict__ C)
{
  __shared__ unsigned short As[2][128 * 64];
  __shared__ unsigned short Bs[2][128 * 64];
  const int tid  = threadIdx.x;
  const int lane = tid & 63;
  const int wave = tid >> 6;
  const int lo   = lane & 15, q4 = lane >> 4;
  const int lo7  = lane & 7;
  const int wm   = wave & 3, wn = wave >> 2;
  const int m0 = blockIdx.y * 128, n0 = blockIdx.x * 128;

  f32x4 acc[2][4] = {};

  auto stage = [&](int k0, int buf) {
#pragma unroll
    for (int i = 0; i < 2; ++i) {
      int ci = i * 512 + tid;
      int row = ci >> 3;
      int c = (ci & 7) ^ (row & 7);
      async16(A + (size_t)(m0 + row) * DMODEL + k0 + c * 8, (char*)As[buf] + ci * 16);
      async16(W + (size_t)(n0 + row) * DMODEL + k0 + c * 8, (char*)Bs[buf] + ci * 16);
    }
  };

  stage(0, 0);
  for (int it = 0; it < DMODEL / 64; ++it) {
    const int buf = it & 1;
    __syncthreads();
    if (it + 1 < DMODEL / 64) stage((it + 1) * 64, buf ^ 1);
#pragma unroll
    for (int hh = 0; hh < 2; ++hh) {
      bf16x8 af[2], bf[4];
#pragma unroll
      for (int mi = 0; mi < 2; ++mi)
        af[mi] = *(const bf16x8*)&As[buf][(wm * 32 + mi * 16 + lo) * 64 + ((hh * 4 + q4) ^ lo7) * 8];
#pragma unroll
      for (int ni = 0; ni < 4; ++ni)
        bf[ni] = *(const bf16x8*)&Bs[buf][(wn * 64 + ni * 16 + lo) * 64 + ((hh * 4 + q4) ^ lo7) * 8];
#pragma unroll
      for (int mi = 0; mi < 2; ++mi)
#pragma unroll
        for (int ni = 0; ni < 4; ++ni)
          acc[mi][ni] = __builtin_amdgcn_mfma_f32_16x16x32_bf16(af[mi], bf[ni], acc[mi][ni], 0, 0, 0);
    }
  }

#pragma unroll
  for (int mi = 0; mi < 2; ++mi)
#pragma unroll
    for (int ni = 0; ni < 4; ++ni)
#pragma unroll
      for (int r = 0; r < 4; ++r) {
        int m = m0 + wm * 32 + mi * 16 + q4 * 4 + r;
        int n = n0 + wn * 64 + ni * 16 + lo;
        C[(size_t)m * DMODEL + n] = acc[mi][ni][r] + bias[n];
      }
}

// Flash attention + ALiBi, fixed-scale softmax, register-resident P (S^T trick),
// exact per-head sliding window (D = 28 exp2-bits), htab load-balancing.
__global__ __launch_bounds__(256, 4) void attn_kernel(
    const unsigned short* __restrict__ Q, const unsigned short* __restrict__ K,
    const unsigned short* __restrict__ Vt, unsigned short* __restrict__ O)
{
  __shared__ unsigned short Ks[2][64 * 64];
  __shared__ unsigned short Vs[2][64 * 64];

  const int tid = threadIdx.x, lane = tid & 63, wave = tid >> 6;
  const int lo = lane & 15, q4 = lane >> 4;
  const int lo7 = lane & 7;
  const int bid = blockIdx.x;
  // htab[s] packed as nibbles: {12,13,14,15,11,10,9,8,4,5,6,7,1,0,2,3}
  const int h  = (int)((0x3201765489ABFEDCull >> ((bid >> 6) * 4)) & 15);
  const int qb = bid & 15;
  const int b  = (bid >> 4) & 3;
  const int bh = b * NHEADS + h;
  const float slopeL = exp2f(-0.5f * (float)(h + 1)) * 1.44269504f;
  const int q0 = qb * 128;
  const int wq0 = q0 + wave * 32;

  // per-head window: keep tiles with min distance <= D = 28/slopeL
  const int D = (int)(19.407f * exp2f(0.5f * (float)(h + 1)));
  int tlo = q0 - D;
  const int ktlo = (tlo <= 0) ? 0 : (tlo >> 6);
  int thi = (q0 + 127 + D) >> 6;
  const int kthi = (thi > TT / 64 - 1) ? TT / 64 - 1 : thi;

  // Q fragments (B-operand of S^T): 2 m-tiles x 2 k-halves
  bf16x8 qf[2][2];
#pragma unroll
  for (int m = 0; m < 2; ++m)
#pragma unroll
    for (int hh = 0; hh < 2; ++hh)
      qf[m][hh] = *(const bf16x8*)(Q + ((size_t)bh * TT + wq0 + m * 16 + lo) * HDIM + hh * 32 + q4 * 8);

  // ones B-fragment for row-sum (K=16): column n==0 only
  bf16x4 ones4;
  {
    short o = (lo == 0) ? (short)0x3F80 : (short)0;
    ones4 = bf16x4{o, o, o, o};
  }

  f32x4 Oacc[2][4];
  f32x4 lacc[2];
#pragma unroll
  for (int m = 0; m < 2; ++m) {
    lacc[m] = f32x4{0.f, 0.f, 0.f, 0.f};
#pragma unroll
    for (int nd = 0; nd < 4; ++nd) Oacc[m][nd] = f32x4{0.f, 0.f, 0.f, 0.f};
  }

  // hoisted distance base: qrow - key = eb[m][r] - (kt*64 + ns*16)
  float eb[2][4];
#pragma unroll
  for (int m = 0; m < 2; ++m)
#pragma unroll
    for (int r = 0; r < 4; ++r)
      eb[m][r] = (float)(wq0 + m * 16 + lo - q4 * 4 - r);

  const unsigned short* kbh = K + (size_t)bh * TT * HDIM;
  const unsigned short* vbh = Vt + (size_t)bh * HDIM * TT;

  auto stage = [&](int kt, int buf) {
#pragma unroll
    for (int i = 0; i < 2; ++i) {
      int ci = i * 256 + tid;
      int row = ci >> 3;
      int c = (ci & 7) ^ (row & 7);
      async16(kbh + (size_t)(kt * 64 + row) * HDIM + c * 8, (char*)Ks[buf] + ci * 16);
      async16(vbh + (size_t)row * TT + kt * 64 + c * 8,     (char*)Vs[buf] + ci * 16);
    }
  };

  stage(ktlo, 0);

  for (int kt = ktlo; kt <= kthi; ++kt) {
    const int buf = (kt - ktlo) & 1;
    __syncthreads();  // tile kt staged; all waves done reading buf^1
    if (kt < kthi) stage(kt + 1, buf ^ 1);

    bf16x4 pa[2][4];  // P A-fragments, [m][ns]

#pragma unroll
    for (int ns = 0; ns < 4; ++ns) {
      const int krow = (ns * 16 + lo) * 64;
      bf16x8 kf0 = *(const bf16x8*)&Ks[buf][krow + ((q4) ^ lo7) * 8];
      bf16x8 kf1 = *(const bf16x8*)&Ks[buf][krow + ((4 + q4) ^ lo7) * 8];
      const float kb = (float)(kt * 64 + ns * 16);
#pragma unroll
      for (int m = 0; m < 2; ++m) {
        // S^T: D[key][qrow], lane: col=lo=qrow, rows=q4*4+r=key-in-block
        f32x4 a = {0.f, 0.f, 0.f, 0.f};
        a = __builtin_amdgcn_mfma_f32_16x16x32_bf16(kf0, qf[m][0], a, 0, 0, 0);
        a = __builtin_amdgcn_mfma_f32_16x16x32_bf16(kf1, qf[m][1], a, 0, 0, 0);
        float p[4];
#pragma unroll
        for (int r = 0; r < 4; ++r) {
          float w = eb[m][r] - kb;                     // qrow - key
          p[r] = EXP2(fmaf(-slopeL, fabsf(w), a[r]));  // a already scaled by c1
        }
        union { bf16x4 v; unsigned int u[2]; } pk;
        pk.u[0] = pkbf(p[0], p[1]);
        pk.u[1] = pkbf(p[2], p[3]);
        pa[m][ns] = pk.v;
      }
    }

    // PV + row-sum, K=16 MFMAs; A = P (m=qrow, k=key), B = Vt rows (n=d, k=key)
#pragma unroll
    for (int ns = 0; ns < 4; ++ns) {
#pragma unroll
      for (int nd = 0; nd < 4; ++nd) {
        const int row = nd * 16 + lo;
        const int swc = ((ns * 2 + (q4 >> 1)) ^ (row & 7));
        bf16x4 vb = *(const bf16x4*)&Vs[buf][row * 64 + swc * 8 + (q4 & 1) * 4];
#pragma unroll
        for (int m = 0; m < 2; ++m)
          Oacc[m][nd] = __builtin_amdgcn_mfma_f32_16x16x16bf16_1k(pa[m][ns], vb, Oacc[m][nd], 0, 0, 0);
      }
#pragma unroll
      for (int m = 0; m < 2; ++m)
        lacc[m] = __builtin_amdgcn_mfma_f32_16x16x16bf16_1k(pa[m][ns], ones4, lacc[m], 0, 0, 0);
    }
  }

  // epilogue: broadcast row-sums from lo==0 lanes, normalize, store
#pragma unroll
  for (int m = 0; m < 2; ++m)
#pragma unroll
    for (int r = 0; r < 4; ++r) {
      float l = __shfl(lacc[m][r], lane & 48);
      float inv = 1.f / l;
      int t = wq0 + m * 16 + q4 * 4 + r;
#pragma unroll
      for (int nd = 0; nd < 4; ++nd) {
        int d = nd * 16 + lo;
        O[((size_t)(b * TT + t)) * DMODEL + h * HDIM + d] = f2bf(Oacc[m][nd][r] * inv);
      }
    }
}

extern "C" void kernel_launch(void* const* d_in, const int* in_sizes, int n_in,
                              void* d_out, int out_size, void* d_ws, size_t ws_size,
                              hipStream_t stream) {
  const float* x  = (const float*)d_in[0];
  const float* wq = (const float*)d_in[1];
  const float* wk = (const float*)d_in[2];
  const float* wv = (const float*)d_in[3];
  const float* wo = (const float*)d_in[4];
  const float* bo = (const float*)d_in[5];
  float* out = (float*)d_out;

  char* ws = (char*)d_ws;
  const size_t seg  = (size_t)BB * TT * DMODEL * sizeof(unsigned short);  // 16.78 MB
  const size_t wseg = (size_t)DMODEL * DMODEL * sizeof(unsigned short);   // 2 MB
  unsigned short* qw    = (unsigned short*)(ws);
  unsigned short* kw    = (unsigned short*)(ws + seg);
  unsigned short* vtw   = (unsigned short*)(ws + 2 * seg);
  unsigned short* ow    = (unsigned short*)(ws + 3 * seg);
  unsigned short* wqkvb = (unsigned short*)(ws + 4 * seg);
  unsigned short* wob   = (unsigned short*)(ws + 4 * seg + 3 * wseg);

  cvt_all<<<dim3(4096), dim3(256), 0, stream>>>(wq, wk, wv, wo, wqkvb, wob);

  gemm_qkv<<<dim3(24, 64), dim3(512), 0, stream>>>(x, wqkvb, qw, kw, vtw);

  attn_kernel<<<dim3(BB * NHEADS * (TT / 128)), dim3(256), 0, stream>>>(qw, kw, vtw, ow);

  gemm_out<<<dim3(8, 64), dim3(512), 0, stream>>>(ow, wob, bo, out);
}

// Round 12
// 250.463 us; speedup vs baseline: 1.1605x; 1.1605x over previous
//
#include <hip/hip_runtime.h>

#define DMODEL 1024
#define NHEADS 16
#define HDIM   64
#define BB     4
#define TT     2048

typedef __attribute__((ext_vector_type(8))) short bf16x8;
typedef __attribute__((ext_vector_type(4))) short bf16x4;
typedef __attribute__((ext_vector_type(4))) float f32x4;

#if __has_builtin(__builtin_amdgcn_exp2f)
#define EXP2(x) __builtin_amdgcn_exp2f(x)
#else
#define EXP2(x) __expf(0.69314718f * (x))
#endif

// 0.125 * log2(e): folded into Q at projection time
#define C1SCALE 0.18033688f

__device__ inline void async16(const void* g, void* l) {
  __builtin_amdgcn_global_load_lds(
      (const __attribute__((address_space(1))) unsigned int*)g,
      (__attribute__((address_space(3))) unsigned int*)l,
      16, 0, 0);
}

__device__ inline unsigned short f2bf(float x) {
  union { float f; unsigned int u; } c; c.f = x;
  unsigned int r = (c.u + 0x7FFFu + ((c.u >> 16) & 1u)) >> 16;
  return (unsigned short)r;
}

// pack two fp32 -> bf16x2, TRUNCATING (P >= 0; identical truncation feeds both
// numerator (PV) and denominator (P*ones) so the uniform bias cancels in O)
__device__ inline unsigned int pkbf(float x, float y) {
  union { float f; unsigned int u; } a, b; a.f = x; b.f = y;
  return __builtin_amdgcn_perm(b.u, a.u, 0x07060302u);
}

// One fused conversion kernel: x (8192 blk), wq/wk/wv -> wqkvb, wo -> wob (1024 blk each)
__global__ __launch_bounds__(256) void cvt_all(
    const float* __restrict__ x,  const float* __restrict__ wq,
    const float* __restrict__ wk, const float* __restrict__ wv,
    const float* __restrict__ wo,
    unsigned short* __restrict__ xb, unsigned short* __restrict__ wqkvb,
    unsigned short* __restrict__ wob)
{
  int bid = blockIdx.x;
  const float* src; unsigned short* dst; size_t off;
  if (bid < 8192) { src = x; dst = xb; off = (size_t)bid * 1024; }
  else {
    int w = (bid - 8192) >> 10, r = (bid - 8192) & 1023;
    off = (size_t)r * 1024;
    if (w == 0)      { src = wq; dst = wqkvb; }
    else if (w == 1) { src = wk; dst = wqkvb + 1048576; }
    else if (w == 2) { src = wv; dst = wqkvb + 2097152; }
    else             { src = wo; dst = wob; }
  }
  size_t i = off + threadIdx.x * 4;
  float4 v = *(const float4*)(src + i);
  ushort4 o;
  o.x = f2bf(v.x); o.y = f2bf(v.y); o.z = f2bf(v.z); o.w = f2bf(v.w);
  *(ushort4*)(dst + i) = o;
}

// Fused QKV projection: A = xb (8192x1024), W = wqkvb (3072x1024), y = A W^T.
// R8 structure: 8 waves x (32x64 per-wave tile, 32 AGPR acc), BK=64,
// XOR-8 swizzle (conflict-free), double-buffered async staging.
// Grid (64, 24): blockIdx.x = m-tile so same-m blocks (which share the A tile)
// have bids spaced 64 apart -> same XCD under round-robin -> A served from L2.
// Q output pre-scaled by C1SCALE.
__global__ __launch_bounds__(512, 4) void gemm_qkv(
    const unsigned short* __restrict__ A, const unsigned short* __restrict__ W,
    unsigned short* __restrict__ qw, unsigned short* __restrict__ kw,
    unsigned short* __restrict__ vtw)
{
  __shared__ unsigned short As[2][128 * 64];
  __shared__ unsigned short Bs[2][128 * 64];
  const int tid  = threadIdx.x;
  const int lane = tid & 63;
  const int wave = tid >> 6;           // 0..7
  const int lo   = lane & 15, q4 = lane >> 4;
  const int lo7  = lane & 7;
  const int wm   = wave & 3, wn = wave >> 2;  // 32-row quarter, 64-col half
  const int m0 = blockIdx.x * 128;            // m-tile on x (XCD locality)
  const int nb = blockIdx.y;                  // 0..23
  const int n0 = nb * 128;
  const int mid = nb >> 3;

  f32x4 acc[2][4] = {};

  auto stage = [&](int k0, int buf) {
#pragma unroll
    for (int i = 0; i < 2; ++i) {
      int ci = i * 512 + tid;          // 0..1023
      int row = ci >> 3;
      int c = (ci & 7) ^ (row & 7);
      async16(A + (size_t)(m0 + row) * DMODEL + k0 + c * 8, (char*)As[buf] + ci * 16);
      async16(W + (size_t)(n0 + row) * DMODEL + k0 + c * 8, (char*)Bs[buf] + ci * 16);
    }
  };

  stage(0, 0);
  for (int it = 0; it < DMODEL / 64; ++it) {
    const int buf = it & 1;
    __syncthreads();  // stage(it), issued one compute phase ago, now resident
    if (it + 1 < DMODEL / 64) stage((it + 1) * 64, buf ^ 1);
#pragma unroll
    for (int hh = 0; hh < 2; ++hh) {
      bf16x8 af[2], bf[4];
#pragma unroll
      for (int mi = 0; mi < 2; ++mi)
        af[mi] = *(const bf16x8*)&As[buf][(wm * 32 + mi * 16 + lo) * 64 + ((hh * 4 + q4) ^ lo7) * 8];
#pragma unroll
      for (int ni = 0; ni < 4; ++ni)
        bf[ni] = *(const bf16x8*)&Bs[buf][(wn * 64 + ni * 16 + lo) * 64 + ((hh * 4 + q4) ^ lo7) * 8];
#pragma unroll
      for (int mi = 0; mi < 2; ++mi)
#pragma unroll
        for (int ni = 0; ni < 4; ++ni)
          acc[mi][ni] = __builtin_amdgcn_mfma_f32_16x16x32_bf16(af[mi], bf[ni], acc[mi][ni], 0, 0, 0);
    }
  }

  unsigned short* dst = (mid == 0) ? qw : (mid == 1) ? kw : vtw;
  const float sc = (mid == 0) ? C1SCALE : 1.0f;
#pragma unroll
  for (int mi = 0; mi < 2; ++mi) {
#pragma unroll
    for (int ni = 0; ni < 4; ++ni) {
#pragma unroll
      for (int r = 0; r < 4; ++r) {
        int m = m0 + wm * 32 + mi * 16 + q4 * 4 + r;
        int nl = ((nb & 7) * 128) + wn * 64 + ni * 16 + lo;
        float v = acc[mi][ni][r] * sc;
        int b = m >> 11, t = m & (TT - 1);
        int h = nl >> 6, d = nl & 63;
        if (mid == 2)
          dst[(((size_t)(b * NHEADS + h)) * HDIM + d) * TT + t] = f2bf(v);
        else
          dst[(((size_t)(b * NHEADS + h)) * TT + t) * HDIM + d] = f2bf(v);
      }
    }
  }
}

// Output projection: C = A W^T + bias, fp32 out. Same R8 dbuf structure,
// grid (64, 8) with m on x for XCD locality of the A (ow) tile.
__global__ __launch_bounds__(512, 4) void gemm_out(
    const unsigned short* __restrict__ A, const unsigned short* __restrict__ W,
    const float* __restrict__ bias, float* __restrict__ C)
{
  __shared__ unsigned short As[2][128 * 64];
  __shared__ unsigned short Bs[2][128 * 64];
  const int tid  = threadIdx.x;
  const int lane = tid & 63;
  const int wave = tid >> 6;
  const int lo   = lane & 15, q4 = lane >> 4;
  const int lo7  = lane & 7;
  const int wm   = wave & 3, wn = wave >> 2;
  const int m0 = blockIdx.x * 128, n0 = blockIdx.y * 128;

  f32x4 acc[2][4] = {};

  auto stage = [&](int k0, int buf) {
#pragma unroll
    for (int i = 0; i < 2; ++i) {
      int ci = i * 512 + tid;
      int row = ci >> 3;
      int c = (ci & 7) ^ (row & 7);
      async16(A + (size_t)(m0 + row) * DMODEL + k0 + c * 8, (char*)As[buf] + ci * 16);
      async16(W + (size_t)(n0 + row) * DMODEL + k0 + c * 8, (char*)Bs[buf] + ci * 16);
    }
  };

  stage(0, 0);
  for (int it = 0; it < DMODEL / 64; ++it) {
    const int buf = it & 1;
    __syncthreads();
    if (it + 1 < DMODEL / 64) stage((it + 1) * 64, buf ^ 1);
#pragma unroll
    for (int hh = 0; hh < 2; ++hh) {
      bf16x8 af[2], bf[4];
#pragma unroll
      for (int mi = 0; mi < 2; ++mi)
        af[mi] = *(const bf16x8*)&As[buf][(wm * 32 + mi * 16 + lo) * 64 + ((hh * 4 + q4) ^ lo7) * 8];
#pragma unroll
      for (int ni = 0; ni < 4; ++ni)
        bf[ni] = *(const bf16x8*)&Bs[buf][(wn * 64 + ni * 16 + lo) * 64 + ((hh * 4 + q4) ^ lo7) * 8];
#pragma unroll
      for (int mi = 0; mi < 2; ++mi)
#pragma unroll
        for (int ni = 0; ni < 4; ++ni)
          acc[mi][ni] = __builtin_amdgcn_mfma_f32_16x16x32_bf16(af[mi], bf[ni], acc[mi][ni], 0, 0, 0);
    }
  }

#pragma unroll
  for (int mi = 0; mi < 2; ++mi)
#pragma unroll
    for (int ni = 0; ni < 4; ++ni)
#pragma unroll
      for (int r = 0; r < 4; ++r) {
        int m = m0 + wm * 32 + mi * 16 + q4 * 4 + r;
        int n = n0 + wn * 64 + ni * 16 + lo;
        C[(size_t)m * DMODEL + n] = acc[mi][ni][r] + bias[n];
      }
}

// Flash attention + ALiBi, fixed-scale softmax, register-resident P (S^T trick),
// exact per-head sliding window (D = 28 exp2-bits), htab load-balancing.
__global__ __launch_bounds__(256, 4) void attn_kernel(
    const unsigned short* __restrict__ Q, const unsigned short* __restrict__ K,
    const unsigned short* __restrict__ Vt, unsigned short* __restrict__ O)
{
  __shared__ unsigned short Ks[2][64 * 64];
  __shared__ unsigned short Vs[2][64 * 64];

  const int tid = threadIdx.x, lane = tid & 63, wave = tid >> 6;
  const int lo = lane & 15, q4 = lane >> 4;
  const int lo7 = lane & 7;
  const int bid = blockIdx.x;
  // htab[s] packed as nibbles: {12,13,14,15,11,10,9,8,4,5,6,7,1,0,2,3}
  const int h  = (int)((0x3201765489ABFEDCull >> ((bid >> 6) * 4)) & 15);
  const int qb = bid & 15;
  const int b  = (bid >> 4) & 3;
  const int bh = b * NHEADS + h;
  const float slopeL = exp2f(-0.5f * (float)(h + 1)) * 1.44269504f;
  const int q0 = qb * 128;
  const int wq0 = q0 + wave * 32;

  // per-head window: keep tiles with min distance <= D = 28/slopeL
  const int D = (int)(19.407f * exp2f(0.5f * (float)(h + 1)));
  int tlo = q0 - D;
  const int ktlo = (tlo <= 0) ? 0 : (tlo >> 6);
  int thi = (q0 + 127 + D) >> 6;
  const int kthi = (thi > TT / 64 - 1) ? TT / 64 - 1 : thi;

  // Q fragments (B-operand of S^T): 2 m-tiles x 2 k-halves
  bf16x8 qf[2][2];
#pragma unroll
  for (int m = 0; m < 2; ++m)
#pragma unroll
    for (int hh = 0; hh < 2; ++hh)
      qf[m][hh] = *(const bf16x8*)(Q + ((size_t)bh * TT + wq0 + m * 16 + lo) * HDIM + hh * 32 + q4 * 8);

  // ones B-fragment for row-sum (K=16): column n==0 only
  bf16x4 ones4;
  {
    short o = (lo == 0) ? (short)0x3F80 : (short)0;
    ones4 = bf16x4{o, o, o, o};
  }

  f32x4 Oacc[2][4];
  f32x4 lacc[2];
#pragma unroll
  for (int m = 0; m < 2; ++m) {
    lacc[m] = f32x4{0.f, 0.f, 0.f, 0.f};
#pragma unroll
    for (int nd = 0; nd < 4; ++nd) Oacc[m][nd] = f32x4{0.f, 0.f, 0.f, 0.f};
  }

  // hoisted distance base: qrow - key = eb[m][r] - (kt*64 + ns*16)
  float eb[2][4];
#pragma unroll
  for (int m = 0; m < 2; ++m)
#pragma unroll
    for (int r = 0; r < 4; ++r)
      eb[m][r] = (float)(wq0 + m * 16 + lo - q4 * 4 - r);

  const unsigned short* kbh = K + (size_t)bh * TT * HDIM;
  const unsigned short* vbh = Vt + (size_t)bh * HDIM * TT;

  auto stage = [&](int kt, int buf) {
#pragma unroll
    for (int i = 0; i < 2; ++i) {
      int ci = i * 256 + tid;
      int row = ci >> 3;
      int c = (ci & 7) ^ (row & 7);
      async16(kbh + (size_t)(kt * 64 + row) * HDIM + c * 8, (char*)Ks[buf] + ci * 16);
      async16(vbh + (size_t)row * TT + kt * 64 + c * 8,     (char*)Vs[buf] + ci * 16);
    }
  };

  stage(ktlo, 0);

  for (int kt = ktlo; kt <= kthi; ++kt) {
    const int buf = (kt - ktlo) & 1;
    __syncthreads();  // tile kt staged; all waves done reading buf^1
    if (kt < kthi) stage(kt + 1, buf ^ 1);

    bf16x4 pa[2][4];  // P A-fragments, [m][ns]

#pragma unroll
    for (int ns = 0; ns < 4; ++ns) {
      const int krow = (ns * 16 + lo) * 64;
      bf16x8 kf0 = *(const bf16x8*)&Ks[buf][krow + ((q4) ^ lo7) * 8];
      bf16x8 kf1 = *(const bf16x8*)&Ks[buf][krow + ((4 + q4) ^ lo7) * 8];
      const float kb = (float)(kt * 64 + ns * 16);
#pragma unroll
      for (int m = 0; m < 2; ++m) {
        // S^T: D[key][qrow], lane: col=lo=qrow, rows=q4*4+r=key-in-block
        f32x4 a = {0.f, 0.f, 0.f, 0.f};
        a = __builtin_amdgcn_mfma_f32_16x16x32_bf16(kf0, qf[m][0], a, 0, 0, 0);
        a = __builtin_amdgcn_mfma_f32_16x16x32_bf16(kf1, qf[m][1], a, 0, 0, 0);
        float p[4];
#pragma unroll
        for (int r = 0; r < 4; ++r) {
          float w = eb[m][r] - kb;                     // qrow - key
          p[r] = EXP2(fmaf(-slopeL, fabsf(w), a[r]));  // a already scaled by c1
        }
        union { bf16x4 v; unsigned int u[2]; } pk;
        pk.u[0] = pkbf(p[0], p[1]);
        pk.u[1] = pkbf(p[2], p[3]);
        pa[m][ns] = pk.v;
      }
    }

    // PV + row-sum, K=16 MFMAs; A = P (m=qrow, k=key), B = Vt rows (n=d, k=key)
#pragma unroll
    for (int ns = 0; ns < 4; ++ns) {
#pragma unroll
      for (int nd = 0; nd < 4; ++nd) {
        const int row = nd * 16 + lo;
        const int swc = ((ns * 2 + (q4 >> 1)) ^ (row & 7));
        bf16x4 vb = *(const bf16x4*)&Vs[buf][row * 64 + swc * 8 + (q4 & 1) * 4];
#pragma unroll
        for (int m = 0; m < 2; ++m)
          Oacc[m][nd] = __builtin_amdgcn_mfma_f32_16x16x16bf16_1k(pa[m][ns], vb, Oacc[m][nd], 0, 0, 0);
      }
#pragma unroll
      for (int m = 0; m < 2; ++m)
        lacc[m] = __builtin_amdgcn_mfma_f32_16x16x16bf16_1k(pa[m][ns], ones4, lacc[m], 0, 0, 0);
    }
  }

  // epilogue: broadcast row-sums from lo==0 lanes, normalize, store
#pragma unroll
  for (int m = 0; m < 2; ++m)
#pragma unroll
    for (int r = 0; r < 4; ++r) {
      float l = __shfl(lacc[m][r], lane & 48);
      float inv = 1.f / l;
      int t = wq0 + m * 16 + q4 * 4 + r;
#pragma unroll
      for (int nd = 0; nd < 4; ++nd) {
        int d = nd * 16 + lo;
        O[((size_t)(b * TT + t)) * DMODEL + h * HDIM + d] = f2bf(Oacc[m][nd][r] * inv);
      }
    }
}

extern "C" void kernel_launch(void* const* d_in, const int* in_sizes, int n_in,
                              void* d_out, int out_size, void* d_ws, size_t ws_size,
                              hipStream_t stream) {
  const float* x  = (const float*)d_in[0];
  const float* wq = (const float*)d_in[1];
  const float* wk = (const float*)d_in[2];
  const float* wv = (const float*)d_in[3];
  const float* wo = (const float*)d_in[4];
  const float* bo = (const float*)d_in[5];
  float* out = (float*)d_out;

  char* ws = (char*)d_ws;
  const size_t seg  = (size_t)BB * TT * DMODEL * sizeof(unsigned short);  // 16.78 MB
  const size_t wseg = (size_t)DMODEL * DMODEL * sizeof(unsigned short);   // 2 MB
  unsigned short* qw    = (unsigned short*)(ws);
  unsigned short* kw    = (unsigned short*)(ws + seg);
  unsigned short* vtw   = (unsigned short*)(ws + 2 * seg);
  unsigned short* ow    = (unsigned short*)(ws + 3 * seg);
  unsigned short* xb    = (unsigned short*)(ws + 4 * seg);
  unsigned short* wqkvb = (unsigned short*)(ws + 5 * seg);
  unsigned short* wob   = (unsigned short*)(ws + 5 * seg + 3 * wseg);

  cvt_all<<<dim3(8192 + 4096), dim3(256), 0, stream>>>(x, wq, wk, wv, wo, xb, wqkvb, wob);

  gemm_qkv<<<dim3(64, 24), dim3(512), 0, stream>>>(xb, wqkvb, qw, kw, vtw);

  attn_kernel<<<dim3(BB * NHEADS * (TT / 128)), dim3(256), 0, stream>>>(qw, kw, vtw, ow);

  gemm_out<<<dim3(64, 8), dim3(512), 0, stream>>>(ow, wob, bo, out);
}